// Round 1
// baseline (121.326 us; speedup 1.0000x reference)
//
#include <hip/hip_runtime.h>
#include <stddef.h>

// NPDCLoss: out[d] = mean_t (x_pred[t,d] - delayed_avg[t,d])^2
//   delayed_avg[t] = (sum_{j=1..m} x_true[t-j] + (NLAG-m)*x_true[t]) / NLAG,
//   m = min(t, NLAG)

#define NS   16384
#define D    2048
#define NLAG 50

#define ROW_CHUNKS     128
#define ROWS_PER_CHUNK (NS / ROW_CHUNKS)   // 128
#define BLOCK          256
#define CPT            2                   // columns per thread (float2)
#define COLS_PER_BLOCK (BLOCK * CPT)       // 512
#define COL_BLOCKS     (D / COLS_PER_BLOCK) // 4

template <bool USE_WS>
__global__ __launch_bounds__(BLOCK) void npdc_partial(
    const float* __restrict__ xp,
    const float* __restrict__ xt,
    float* __restrict__ partial,   // [ROW_CHUNKS][D] when USE_WS
    float* __restrict__ out)       // [D] atomic path when !USE_WS
{
    const int cb  = blockIdx.x;                       // column block
    const int rc  = blockIdx.y;                       // row chunk
    const int col = cb * COLS_PER_BLOCK + (int)threadIdx.x * CPT;
    const int r0  = rc * ROWS_PER_CHUNK;
    const int r1  = r0 + ROWS_PER_CHUNK;

    // ---- init window sum: rows max(0, r0-NLAG) .. r0-1 ----
    float wx = 0.0f, wy = 0.0f;
    int jstart = r0 - NLAG;
    if (jstart < 0) jstart = 0;
    for (int j = jstart; j < r0; ++j) {
        float2 v = *reinterpret_cast<const float2*>(&xt[(size_t)j * D + col]);
        wx += v.x; wy += v.y;
    }

    float ax = 0.0f, ay = 0.0f;
    const float inv_n = 1.0f / (float)NLAG;

    #pragma unroll 4
    for (int t = r0; t < r1; ++t) {
        float2 p = *reinterpret_cast<const float2*>(&xp[(size_t)t * D + col]);
        float2 c = *reinterpret_cast<const float2*>(&xt[(size_t)t * D + col]);
        // fac is nonzero only for t < NLAG (chunk 0 warm-up); wave-uniform.
        float fac = (t < NLAG) ? (float)(NLAG - t) : 0.0f;
        float dx = (wx + fac * c.x) * inv_n;
        float dy = (wy + fac * c.y) * inv_n;
        float ex = p.x - dx;
        float ey = p.y - dy;
        ax += ex * ex;
        ay += ey * ey;
        // slide window forward
        wx += c.x; wy += c.y;
        if (t >= NLAG) {  // uniform branch; only false during chunk-0 warm-up
            float2 o = *reinterpret_cast<const float2*>(&xt[(size_t)(t - NLAG) * D + col]);
            wx -= o.x; wy -= o.y;
        }
    }

    if (USE_WS) {
        float2 r; r.x = ax; r.y = ay;
        *reinterpret_cast<float2*>(&partial[(size_t)rc * D + col]) = r;
    } else {
        const float inv_ns = 1.0f / (float)NS;
        atomicAdd(&out[col],     ax * inv_ns);
        atomicAdd(&out[col + 1], ay * inv_ns);
    }
}

__global__ __launch_bounds__(BLOCK) void npdc_reduce(
    const float* __restrict__ partial, float* __restrict__ out)
{
    const int d = blockIdx.x * BLOCK + (int)threadIdx.x;
    float s = 0.0f;
    #pragma unroll 8
    for (int c = 0; c < ROW_CHUNKS; ++c)
        s += partial[(size_t)c * D + d];
    out[d] = s * (1.0f / (float)NS);
}

__global__ __launch_bounds__(BLOCK) void npdc_zero(float* __restrict__ out)
{
    const int d = blockIdx.x * BLOCK + (int)threadIdx.x;
    if (d < D) out[d] = 0.0f;
}

extern "C" void kernel_launch(void* const* d_in, const int* in_sizes, int n_in,
                              void* d_out, int out_size, void* d_ws, size_t ws_size,
                              hipStream_t stream)
{
    const float* xp = (const float*)d_in[0];   // x_pred [NS, D]
    const float* xt = (const float*)d_in[1];   // x_true [NS, D]
    float* out = (float*)d_out;                // [D]

    const size_t ws_needed = (size_t)ROW_CHUNKS * D * sizeof(float);
    dim3 grid(COL_BLOCKS, ROW_CHUNKS);

    if (ws_size >= ws_needed) {
        float* partial = (float*)d_ws;
        npdc_partial<true><<<grid, BLOCK, 0, stream>>>(xp, xt, partial, out);
        npdc_reduce<<<D / BLOCK, BLOCK, 0, stream>>>(partial, out);
    } else {
        npdc_zero<<<(D + BLOCK - 1) / BLOCK, BLOCK, 0, stream>>>(out);
        npdc_partial<false><<<grid, BLOCK, 0, stream>>>(xp, xt, nullptr, out);
    }
}

// Round 2
// 97.915 us; speedup vs baseline: 1.2391x; 1.2391x over previous
//
#include <hip/hip_runtime.h>
#include <stddef.h>

// NPDCLoss: out[d] = mean_t (x_pred[t,d] - delayed_avg[t,d])^2
//   delayed_avg[t] = (sum_{j=1..m} x_true[t-j] + (NLAG-m)*x_true[t]) / NLAG,
//   m = min(t, NLAG)

#define NS   16384
#define D    2048
#define NLAG 50

#define ROW_CHUNKS     512
#define ROWS_PER_CHUNK (NS / ROW_CHUNKS)    // 32
#define BLOCK          256
#define CPT            4                    // columns per thread (float4)
#define COLS_PER_BLOCK (BLOCK * CPT)        // 1024
#define COL_BLOCKS     (D / COLS_PER_BLOCK) // 2

__device__ __forceinline__ float4 ld4(const float* p) {
    return *reinterpret_cast<const float4*>(p);
}

template <bool USE_WS>
__global__ __launch_bounds__(BLOCK) void npdc_partial(
    const float* __restrict__ xp,
    const float* __restrict__ xt,
    float* __restrict__ partial,   // [ROW_CHUNKS][D] when USE_WS
    float* __restrict__ out)       // [D] atomic path when !USE_WS
{
    const int cb  = blockIdx.x;
    const int rc  = blockIdx.y;
    const int col = cb * COLS_PER_BLOCK + (int)threadIdx.x * CPT;
    const int r0  = rc * ROWS_PER_CHUNK;
    const float inv_n = 1.0f / (float)NLAG;

    // ---- warm-up: window sum of rows max(0, r0-NLAG) .. r0-1 ----
    float wx = 0.f, wy = 0.f, wz = 0.f, ww = 0.f;
    int jstart = r0 - NLAG;
    if (jstart < 0) jstart = 0;
    #pragma unroll 5
    for (int j = jstart; j < r0; ++j) {
        float4 v = ld4(&xt[(size_t)j * D + col]);
        wx += v.x; wy += v.y; wz += v.z; ww += v.w;
    }

    float ax = 0.f, ay = 0.f, az = 0.f, aw = 0.f;

    if (r0 >= NLAG) {
        // hot path: branch-free, t-NLAG always valid, fac == 0
        #pragma unroll 8
        for (int t = r0; t < r0 + ROWS_PER_CHUNK; ++t) {
            float4 p = ld4(&xp[(size_t)t * D + col]);
            float4 c = ld4(&xt[(size_t)t * D + col]);
            float4 o = ld4(&xt[(size_t)(t - NLAG) * D + col]);
            float ex = p.x - wx * inv_n;
            float ey = p.y - wy * inv_n;
            float ez = p.z - wz * inv_n;
            float ew = p.w - ww * inv_n;
            ax += ex * ex; ay += ey * ey; az += ez * ez; aw += ew * ew;
            wx += c.x - o.x; wy += c.y - o.y; wz += c.z - o.z; ww += c.w - o.w;
        }
    } else {
        // warm-up chunks (t may be < NLAG)
        for (int t = r0; t < r0 + ROWS_PER_CHUNK; ++t) {
            float4 p = ld4(&xp[(size_t)t * D + col]);
            float4 c = ld4(&xt[(size_t)t * D + col]);
            float fac = (t < NLAG) ? (float)(NLAG - t) : 0.0f;
            float ex = p.x - (wx + fac * c.x) * inv_n;
            float ey = p.y - (wy + fac * c.y) * inv_n;
            float ez = p.z - (wz + fac * c.z) * inv_n;
            float ew = p.w - (ww + fac * c.w) * inv_n;
            ax += ex * ex; ay += ey * ey; az += ez * ez; aw += ew * ew;
            wx += c.x; wy += c.y; wz += c.z; ww += c.w;
            if (t >= NLAG) {
                float4 o = ld4(&xt[(size_t)(t - NLAG) * D + col]);
                wx -= o.x; wy -= o.y; wz -= o.z; ww -= o.w;
            }
        }
    }

    if (USE_WS) {
        float4 r; r.x = ax; r.y = ay; r.z = az; r.w = aw;
        *reinterpret_cast<float4*>(&partial[(size_t)rc * D + col]) = r;
    } else {
        const float inv_ns = 1.0f / (float)NS;
        atomicAdd(&out[col],     ax * inv_ns);
        atomicAdd(&out[col + 1], ay * inv_ns);
        atomicAdd(&out[col + 2], az * inv_ns);
        atomicAdd(&out[col + 3], aw * inv_ns);
    }
}

// Reduce [ROW_CHUNKS][D] -> [D].  Grid: D/64 blocks of 256 threads.
// Each block: 64 columns x 4 chunk-groups (128 chunks each) + LDS combine.
__global__ __launch_bounds__(BLOCK) void npdc_reduce(
    const float* __restrict__ partial, float* __restrict__ out)
{
    const int dl = (int)threadIdx.x & 63;
    const int g  = (int)threadIdx.x >> 6;          // 0..3
    const int d  = blockIdx.x * 64 + dl;
    const int c0 = g * (ROW_CHUNKS / 4);

    float s = 0.0f;
    #pragma unroll 16
    for (int c = c0; c < c0 + ROW_CHUNKS / 4; ++c)
        s += partial[(size_t)c * D + d];

    __shared__ float sm[4][64];
    sm[g][dl] = s;
    __syncthreads();
    if (g == 0) {
        float t = sm[0][dl] + sm[1][dl] + sm[2][dl] + sm[3][dl];
        out[d] = t * (1.0f / (float)NS);
    }
}

__global__ __launch_bounds__(BLOCK) void npdc_zero(float* __restrict__ out)
{
    const int d = blockIdx.x * BLOCK + (int)threadIdx.x;
    if (d < D) out[d] = 0.0f;
}

extern "C" void kernel_launch(void* const* d_in, const int* in_sizes, int n_in,
                              void* d_out, int out_size, void* d_ws, size_t ws_size,
                              hipStream_t stream)
{
    const float* xp = (const float*)d_in[0];   // x_pred [NS, D]
    const float* xt = (const float*)d_in[1];   // x_true [NS, D]
    float* out = (float*)d_out;                // [D]

    const size_t ws_needed = (size_t)ROW_CHUNKS * D * sizeof(float);
    dim3 grid(COL_BLOCKS, ROW_CHUNKS);

    if (ws_size >= ws_needed) {
        float* partial = (float*)d_ws;
        npdc_partial<true><<<grid, BLOCK, 0, stream>>>(xp, xt, partial, out);
        npdc_reduce<<<D / 64, BLOCK, 0, stream>>>(partial, out);
    } else {
        npdc_zero<<<(D + BLOCK - 1) / BLOCK, BLOCK, 0, stream>>>(out);
        npdc_partial<false><<<grid, BLOCK, 0, stream>>>(xp, xt, nullptr, out);
    }
}